// Round 1
// baseline (835.466 us; speedup 1.0000x reference)
//
#include <hip/hip_runtime.h>
#include <cstddef>
#include <cstdint>

// SpatialEmbLoss on MI355X.
// H=W=768, 2 images, NC=5 classes, MAX_ID=3 -> 15 (class,id) pairs per image.
// Lovasz hinge computed exactly-enough via 2048-bin error histogram:
//   lov = integral_0^2 jac(t) dt,  jac(t) = 1 - (gts - n_in(t))/(gts + n_out(t))
// (jac monotone 0->1, tie-order invariant; trapezoid error <= 1/BINS per instance).

#define HH 768
#define WW 768
#define NPIX (HH*WW)            // 589824
#define NCL 5
#define MAXID 3
#define PAIRS (NCL*MAXID)       // 15
#define NIMG 2
#define NCH 9                   // 2 emb + 2 sigma + 5 seed channels
#define BINS 2048
#define NB5 72                  // chunks per (img,pair) in k_hist
#define PXB 8192                // pixels per k_hist block (72*8192 = NPIX)

struct WS {
  unsigned long long argkey[NIMG][PAIRS];   // init 0xFF (atomicMin keys)
  // ---------- zero region from here ----------
  unsigned int cnt[NIMG][PAIRS];
  unsigned int colhist[NIMG][PAIRS][WW];
  unsigned int rowhist[NIMG][PAIRS][HH];
  float sigsum0[NIMG][PAIRS];
  float sigsum1[NIMG][PAIRS];
  float seedT[NIMG];            // sum over pixels,classes of sigmoid^2
  float seedOwn[NIMG];          // sum over pixels of own-class sigmoid^2
  unsigned int hin[NIMG][PAIRS][BINS];
  unsigned int hout[NIMG][PAIRS][BINS];
  float varsum[NIMG][PAIRS];
  float seedin[NIMG][PAIRS];
  float medx[NIMG][PAIRS], medy[NIMG][PAIRS];
  float s0a[NIMG][PAIRS], s1a[NIMG][PAIRS];
  float sm0a[NIMG][PAIRS], sm1a[NIMG][PAIRS];
  float validf[NIMG][PAIRS], cntf[NIMG][PAIRS];
  float lov[NIMG][PAIRS];
  // ---------- end zero region ----------
  float emb0[NIMG][NPIX];       // tanh(pred0)+x  (precomputed in pass1)
  float emb1[NIMG][NPIX];       // tanh(pred1)+y
};

__device__ __forceinline__ float basef(int i) {
  // jnp.linspace(0,1,1024)[i]
  return (float)i * (1.0f / 1023.0f);
}

__device__ __forceinline__ int pair_of(int l, int it) {
  return (l >= 1 && l <= NCL && it >= 1 && it <= MAXID) ? (l - 1) * MAXID + (it - 1) : -1;
}

// ---------------- pass 1: counts, row/col hists, sigma sums, seed sums, emb precompute
__global__ __launch_bounds__(256) void k_pass1(const float* __restrict__ pred,
                                               const int* __restrict__ inst,
                                               const int* __restrict__ lab,
                                               WS* __restrict__ ws) {
  int bid = blockIdx.x;                 // NIMG*HH*3 blocks
  int img = bid / (HH * 3);
  int r = bid % (HH * 3);
  int y = r / 3;
  int x = (r % 3) * 256 + threadIdx.x;
  int pix = y * WW + x;
  const float* p = pred + (size_t)img * NCH * NPIX;
  int l = lab[img * NPIX + pix];
  int it = inst[img * NPIX + pix];

  // seed maps: sigmoid(pred[4+c])
  float t = 0.f, own = 0.f;
#pragma unroll
  for (int c = 0; c < NCL; ++c) {
    float z = p[(4 + c) * NPIX + pix];
    float s = 1.f / (1.f + __expf(-z));
    float s2 = s * s;
    t += s2;
    if (l == c + 1) own = s2;
  }

  // embedding precompute
  float e0 = tanhf(p[0 * NPIX + pix]) + basef(x);
  float e1 = tanhf(p[1 * NPIX + pix]) + basef(y);
  ws->emb0[img][pix] = e0;
  ws->emb1[img][pix] = e1;

  int pr = pair_of(l, it);

  __shared__ unsigned int scnt[PAIRS];
  __shared__ float ssig0[PAIRS], ssig1[PAIRS];
  if (threadIdx.x < PAIRS) { scnt[threadIdx.x] = 0; ssig0[threadIdx.x] = 0.f; ssig1[threadIdx.x] = 0.f; }
  __syncthreads();

  if (pr >= 0) {
    atomicAdd(&scnt[pr], 1u);
    float g0 = p[2 * NPIX + pix];
    float g1 = p[3 * NPIX + pix];
    atomicAdd(&ssig0[pr], g0);
    atomicAdd(&ssig1[pr], g1);
    atomicAdd(&ws->colhist[img][pr][x], 1u);   // distinct x per thread -> low contention
  }

  // wave-reduce seed scalars, one global atomic per wave
  for (int off = 32; off; off >>= 1) { t += __shfl_down(t, off); own += __shfl_down(own, off); }
  if ((threadIdx.x & 63) == 0) {
    atomicAdd(&ws->seedT[img], t);
    atomicAdd(&ws->seedOwn[img], own);
  }

  __syncthreads();
  if (threadIdx.x < PAIRS) {
    unsigned int c = scnt[threadIdx.x];
    if (c) {
      atomicAdd(&ws->cnt[img][threadIdx.x], c);
      atomicAdd(&ws->rowhist[img][threadIdx.x][y], c);
      atomicAdd(&ws->sigsum0[img][threadIdx.x], ssig0[threadIdx.x]);
      atomicAdd(&ws->sigsum1[img][threadIdx.x], ssig1[threadIdx.x]);
    }
  }
}

// ---------------- pass 2: medians from histograms, sigma means, s=exp(10*mean)
__global__ void k_medoid(WS* __restrict__ ws) {
  int t = threadIdx.x;
  if (t >= NIMG * PAIRS) return;
  int img = t / PAIRS, p = t % PAIRS;
  unsigned int c = ws->cnt[img][p];
  float vf = (c > 0) ? 1.f : 0.f;
  float cf = (c > 0) ? (float)c : 1.f;
  unsigned int mid = (c > 0) ? ((c - 1u) >> 1) : 0u;  // lower median index
  int cx = 0, cy = 0;
  unsigned int acc = 0;
  for (int i = 0; i < WW; i++) { acc += ws->colhist[img][p][i]; if (acc > mid) { cx = i; break; } }
  acc = 0;
  for (int i = 0; i < HH; i++) { acc += ws->rowhist[img][p][i]; if (acc > mid) { cy = i; break; } }
  float sm0 = ws->sigsum0[img][p] / cf;
  float sm1 = ws->sigsum1[img][p] / cf;
  ws->medx[img][p] = basef(cx);
  ws->medy[img][p] = basef(cy);
  ws->sm0a[img][p] = sm0;
  ws->sm1a[img][p] = sm1;
  ws->s0a[img][p] = __expf(10.f * sm0);
  ws->s1a[img][p] = __expf(10.f * sm1);
  ws->validf[img][p] = vf;
  ws->cntf[img][p] = cf;
}

// ---------------- pass 3: medoid argmin (first-index tie-break via 64-bit key)
__global__ __launch_bounds__(256) void k_argmin(const int* __restrict__ inst,
                                                const int* __restrict__ lab,
                                                WS* __restrict__ ws) {
  __shared__ unsigned long long skey[PAIRS];
  if (threadIdx.x < PAIRS) skey[threadIdx.x] = ~0ULL;
  __syncthreads();
  int idx = blockIdx.x * 256 + threadIdx.x;    // < NIMG*NPIX, blocks never straddle images
  int img = idx / NPIX;
  int pix = idx - img * NPIX;
  int l = lab[idx], it = inst[idx];
  int pr = pair_of(l, it);
  if (pr >= 0) {
    int x = pix % WW, y = pix / WW;
    float dx = basef(x) - ws->medx[img][pr];
    float dy = basef(y) - ws->medy[img][pr];
    float d = dx * dx + dy * dy;
    unsigned long long key = ((unsigned long long)__float_as_uint(d) << 32) | (unsigned int)pix;
    atomicMin(&skey[pr], key);
  }
  __syncthreads();
  if (threadIdx.x < PAIRS && skey[threadIdx.x] != ~0ULL)
    atomicMin(&ws->argkey[img][threadIdx.x], skey[threadIdx.x]);
}

// ---------------- pass 4 (heavy): per-(img,pair) dist map -> error histograms; fused var/seed_in
__global__ __launch_bounds__(256) void k_hist(const float* __restrict__ pred,
                                              const int* __restrict__ inst,
                                              const int* __restrict__ lab,
                                              WS* __restrict__ ws) {
  int chunk = blockIdx.x;    // 0..NB5-1
  int p = blockIdx.y;        // 0..PAIRS-1
  int img = blockIdx.z;      // 0..NIMG-1
  __shared__ unsigned int hin_s[BINS];
  __shared__ unsigned int hout_s[2 * BINS];   // 2 lane-parity sub-copies
  for (int k = threadIdx.x; k < BINS; k += 256) hin_s[k] = 0;
  for (int k = threadIdx.x; k < 2 * BINS; k += 256) hout_s[k] = 0;
  __syncthreads();
  if (ws->cnt[img][p] == 0) return;   // uniform across block

  unsigned long long key = ws->argkey[img][p];
  int imin = (int)(key & 0xffffffffu);
  float cx = basef(imin % WW);
  float cy = basef(imin / WW);
  float S0 = ws->s0a[img][p], S1 = ws->s1a[img][p];
  float m0 = ws->sm0a[img][p], m1 = ws->sm1a[img][p];
  int ci = p / MAXID;
  int cl = ci + 1, iid = (p % MAXID) + 1;
  const float* pb = pred + (size_t)img * NCH * NPIX;
  const int* lb = lab + img * NPIX;
  const int* ib = inst + img * NPIX;
  const float* e0b = ws->emb0[img];
  const float* e1b = ws->emb1[img];

  float vpart = 0.f, spart = 0.f;
  int base = chunk * PXB;
  int sub = (threadIdx.x & 1) * BINS;
#pragma unroll 4
  for (int i = 0; i < PXB / 256; i++) {
    int pix = base + i * 256 + threadIdx.x;
    float dx = e0b[pix] - cx;
    float dy = e1b[pix] - cy;
    float q = dx * dx * S0 + dy * dy * S1;
    float d = __expf(-q);
    bool m = (lb[pix] == cl) && (ib[pix] == iid);
    float e = m ? (2.f - 2.f * d) : (2.f * d);
    int bin = (int)(e * (BINS * 0.5f));
    bin = bin > (BINS - 1) ? (BINS - 1) : (bin < 0 ? 0 : bin);
    if (m) {
      atomicAdd(&hin_s[bin], 1u);
      float g0 = pb[2 * NPIX + pix] - m0;
      float g1 = pb[3 * NPIX + pix] - m1;
      vpart += g0 * g0 + g1 * g1;
      float sd = 1.f / (1.f + __expf(-pb[(4 + ci) * NPIX + pix])) - d;
      spart += sd * sd;
    } else {
      atomicAdd(&hout_s[sub + bin], 1u);
    }
  }
  __syncthreads();
  for (int k = threadIdx.x; k < BINS; k += 256) {
    unsigned int v = hin_s[k];
    if (v) atomicAdd(&ws->hin[img][p][k], v);
    unsigned int w2 = hout_s[k] + hout_s[BINS + k];
    if (w2) atomicAdd(&ws->hout[img][p][k], w2);
  }
  for (int off = 32; off; off >>= 1) { vpart += __shfl_down(vpart, off); spart += __shfl_down(spart, off); }
  if ((threadIdx.x & 63) == 0) {
    atomicAdd(&ws->varsum[img][p], vpart);
    atomicAdd(&ws->seedin[img][p], spart);
  }
}

// ---------------- pass 5: lovasz = (2/BINS) * (0.5 + sum_{k=1}^{B-1} jac(edge_k))
__global__ __launch_bounds__(256) void k_lovasz(WS* __restrict__ ws) {
  int b = blockIdx.x / PAIRS, p = blockIdx.x % PAIRS;
  unsigned int gts = ws->cnt[b][p];
  if (gts == 0) { if (threadIdx.x == 0) ws->lov[b][p] = 0.f; return; }
  __shared__ unsigned int tin[256], tout[256];
  unsigned int lin[8], lout[8];
  unsigned int si = 0, so = 0;
  int k0 = threadIdx.x * 8;
#pragma unroll
  for (int j = 0; j < 8; j++) {
    lin[j] = ws->hin[b][p][k0 + j];
    lout[j] = ws->hout[b][p][k0 + j];
    si += lin[j]; so += lout[j];
  }
  tin[threadIdx.x] = si; tout[threadIdx.x] = so;
  __syncthreads();
  if (threadIdx.x == 0) {   // exclusive suffix scan of per-thread totals (256 iters, fine)
    unsigned int ri = 0, ro = 0;
    for (int t = 255; t >= 0; t--) {
      unsigned int a = tin[t], c = tout[t];
      tin[t] = ri; tout[t] = ro;
      ri += a; ro += c;
    }
  }
  __syncthreads();
  unsigned int Sin = tin[threadIdx.x], Sout = tout[threadIdx.x];
  float gtsf = (float)gts;
  float js = 0.f;
#pragma unroll
  for (int j = 7; j >= 0; j--) {
    Sin += lin[j]; Sout += lout[j];
    int k = k0 + j;
    if (k >= 1) {
      float jac = 1.f - (float)(gts - Sin) / (gtsf + (float)Sout);
      js += jac;
    }
  }
  for (int off = 32; off; off >>= 1) js += __shfl_down(js, off);
  __shared__ float wsum[4];
  if ((threadIdx.x & 63) == 0) wsum[threadIdx.x >> 6] = js;
  __syncthreads();
  if (threadIdx.x == 0) {
    float s = wsum[0] + wsum[1] + wsum[2] + wsum[3];
    ws->lov[b][p] = (2.f / BINS) * (0.5f + s);
  }
}

// ---------------- pass 6: combine
__global__ void k_final(WS* __restrict__ ws, float* __restrict__ out) {
  if (threadIdx.x == 0 && blockIdx.x == 0) {
    float tot = 0.f;
    for (int b = 0; b < NIMG; b++) {
      float lovs = 0.f, vars = 0.f, sins = 0.f, objs = 0.f;
      for (int p = 0; p < PAIRS; p++) {
        float vf = ws->validf[b][p];
        objs += vf;
        lovs += vf * ws->lov[b][p];
        vars += vf * ws->varsum[b][p] / (ws->cntf[b][p] * 2.f);  // /(cnts*NS)
        sins += vf * ws->seedin[b][p];                            // class_weight = 1
      }
      if (objs < 1.f) objs = 1.f;
      float seed_bg = ws->seedT[b] - ws->seedOwn[b];
      float seed_loss = (seed_bg + sins) / (float)NPIX;
      tot += lovs / objs + 10.f * vars / objs + seed_loss;
    }
    out[0] = tot * 0.5f;
  }
}

extern "C" void kernel_launch(void* const* d_in, const int* in_sizes, int n_in,
                              void* d_out, int out_size, void* d_ws, size_t ws_size,
                              hipStream_t stream) {
  const float* pred = (const float*)d_in[0];
  const int* inst = (const int*)d_in[1];
  const int* lab = (const int*)d_in[2];
  WS* ws = (WS*)d_ws;

  size_t zoff = offsetof(WS, cnt);
  size_t zend = offsetof(WS, emb0);
  hipMemsetAsync((char*)d_ws, 0xFF, zoff, stream);                 // argmin keys -> u64 max
  hipMemsetAsync((char*)d_ws + zoff, 0, zend - zoff, stream);      // accumulators -> 0

  k_pass1<<<dim3(NIMG * HH * 3), 256, 0, stream>>>(pred, inst, lab, ws);
  k_medoid<<<1, 64, 0, stream>>>(ws);
  k_argmin<<<dim3(NIMG * NPIX / 256), 256, 0, stream>>>(inst, lab, ws);
  k_hist<<<dim3(NB5, PAIRS, NIMG), 256, 0, stream>>>(pred, inst, lab, ws);
  k_lovasz<<<dim3(NIMG * PAIRS), 256, 0, stream>>>(ws);
  k_final<<<1, 64, 0, stream>>>(ws, (float*)d_out);
}

// Round 2
// 304.253 us; speedup vs baseline: 2.7460x; 2.7460x over previous
//
#include <hip/hip_runtime.h>
#include <cstddef>
#include <cstdint>

// SpatialEmbLoss on MI355X.
// H=W=768, 2 images, NC=5 classes, MAX_ID=3 -> 15 (class,id) pairs per image.
// Lovasz hinge via 2048-bin error histogram:
//   lov = integral_0^2 jac(t) dt,  jac(t) = 1 - (gts - n_in(t))/(gts + n_out(t))
// Round 2: de-serialize atomics. k_pass1 was 511us at 1.5% HBM / 1.5% VALU ->
// same-address global f32 atomic chains (36K RMWs to 4 addresses). Now: block-
// level accumulation, one atomic per block per scalar (192-deep chains).

#define HH 768
#define WW 768
#define NPIX (HH*WW)            // 589824
#define NCL 5
#define MAXID 3
#define PAIRS (NCL*MAXID)       // 15
#define NIMG 2
#define NCH 9                   // 2 emb + 2 sigma + 5 seed channels
#define BINS 2048
#define PXB 32768               // pixels per k_hist block
#define NB5 (NPIX/PXB)          // 18 chunks per (img,pair)

struct WS {
  unsigned long long argkey[NIMG][PAIRS];   // init 0xFF (atomicMin keys)
  // ---------- zero region from here ----------
  unsigned int cnt[NIMG][PAIRS];
  unsigned int colhist[NIMG][PAIRS][WW];
  unsigned int rowhist[NIMG][PAIRS][HH];
  float sigsum0[NIMG][PAIRS];
  float sigsum1[NIMG][PAIRS];
  float seedT[NIMG];            // sum over pixels,classes of sigmoid^2
  float seedOwn[NIMG];          // sum over pixels of own-class sigmoid^2
  alignas(8) unsigned int hin[NIMG][PAIRS][BINS];
  alignas(8) unsigned int hout[NIMG][PAIRS][BINS];
  float varsum[NIMG][PAIRS];
  float seedin[NIMG][PAIRS];
  float medx[NIMG][PAIRS], medy[NIMG][PAIRS];
  float s0a[NIMG][PAIRS], s1a[NIMG][PAIRS];
  float sm0a[NIMG][PAIRS], sm1a[NIMG][PAIRS];
  float validf[NIMG][PAIRS], cntf[NIMG][PAIRS];
  float lov[NIMG][PAIRS];
  // ---------- end zero region ----------
  float emb0[NIMG][NPIX];       // tanh(pred0)+x  (precomputed in pass1)
  float emb1[NIMG][NPIX];       // tanh(pred1)+y
};

__device__ __forceinline__ float basef(int i) {
  // jnp.linspace(0,1,1024)[i]
  return (float)i * (1.0f / 1023.0f);
}

__device__ __forceinline__ int pair_of(int l, int it) {
  return (l >= 1 && l <= NCL && it >= 1 && it <= MAXID) ? (l - 1) * MAXID + (it - 1) : -1;
}

// ---------------- pass 1: counts, row/col hists, sigma sums, seed sums, emb precompute
// 4 rows per block, 12 px/thread; all pair-stats block-accumulated, ONE global
// atomic per block per counter (depth 192 per address instead of thousands).
__global__ __launch_bounds__(256) void k_pass1(const float* __restrict__ pred,
                                               const int* __restrict__ inst,
                                               const int* __restrict__ lab,
                                               WS* __restrict__ ws) {
  int img = blockIdx.y;
  int y0 = blockIdx.x * 4;
  const float* p = pred + (size_t)img * NCH * NPIX;
  const int* lb = lab + img * NPIX;
  const int* ib = inst + img * NPIX;

  __shared__ unsigned int scnt[PAIRS];
  __shared__ float ssig0[PAIRS], ssig1[PAIRS];
  __shared__ unsigned int srow[4 * PAIRS];
  __shared__ float sT, sO;
  if (threadIdx.x < PAIRS) { scnt[threadIdx.x] = 0; ssig0[threadIdx.x] = 0.f; ssig1[threadIdx.x] = 0.f; }
  if (threadIdx.x < 4 * PAIRS) srow[threadIdx.x] = 0;
  if (threadIdx.x == 0) { sT = 0.f; sO = 0.f; }
  __syncthreads();

  float t = 0.f, own = 0.f;
#pragma unroll
  for (int i = 0; i < 12; i++) {
    int off = i * 256 + threadIdx.x;       // 0..3071
    int rl = off / WW;                      // 0..3
    int x = off - rl * WW;
    int y = y0 + rl;
    int pix = y0 * WW + off;
    int l = lb[pix];
    int it = ib[pix];

    // seed maps: sigmoid(pred[4+c])^2
#pragma unroll
    for (int c = 0; c < NCL; ++c) {
      float z = p[(4 + c) * NPIX + pix];
      float s = 1.f / (1.f + __expf(-z));
      float s2 = s * s;
      t += s2;
      if (l == c + 1) own = own + s2;
    }

    // embedding precompute
    ws->emb0[img][pix] = tanhf(p[0 * NPIX + pix]) + basef(x);
    ws->emb1[img][pix] = tanhf(p[1 * NPIX + pix]) + basef(y);

    int pr = pair_of(l, it);
    if (pr >= 0) {
      atomicAdd(&scnt[pr], 1u);
      atomicAdd(&ssig0[pr], p[2 * NPIX + pix]);
      atomicAdd(&ssig1[pr], p[3 * NPIX + pix]);
      atomicAdd(&srow[rl * PAIRS + pr], 1u);
      atomicAdd(&ws->colhist[img][pr][x], 1u);   // spread over 11520 addrs
    }
  }

  // seed scalars: wave reduce -> LDS -> one global atomic per block
  for (int o = 32; o; o >>= 1) { t += __shfl_down(t, o); own += __shfl_down(own, o); }
  if ((threadIdx.x & 63) == 0) { atomicAdd(&sT, t); atomicAdd(&sO, own); }
  __syncthreads();
  if (threadIdx.x == 0) {
    atomicAdd(&ws->seedT[img], sT);
    atomicAdd(&ws->seedOwn[img], sO);
  }
  if (threadIdx.x < PAIRS) {
    unsigned int c = scnt[threadIdx.x];
    if (c) {
      atomicAdd(&ws->cnt[img][threadIdx.x], c);
      atomicAdd(&ws->sigsum0[img][threadIdx.x], ssig0[threadIdx.x]);
      atomicAdd(&ws->sigsum1[img][threadIdx.x], ssig1[threadIdx.x]);
    }
  }
  if (threadIdx.x < 4 * PAIRS) {
    unsigned int v = srow[threadIdx.x];
    if (v) {
      int rl = threadIdx.x / PAIRS, pr = threadIdx.x % PAIRS;
      atomicAdd(&ws->rowhist[img][pr][y0 + rl], v);
    }
  }
}

// ---------------- pass 2: medians from histograms, sigma means, s=exp(10*mean)
__global__ void k_medoid(WS* __restrict__ ws) {
  int t = threadIdx.x;
  if (t >= NIMG * PAIRS) return;
  int img = t / PAIRS, p = t % PAIRS;
  unsigned int c = ws->cnt[img][p];
  float vf = (c > 0) ? 1.f : 0.f;
  float cf = (c > 0) ? (float)c : 1.f;
  unsigned int mid = (c > 0) ? ((c - 1u) >> 1) : 0u;  // lower median index
  int cx = 0, cy = 0;
  unsigned int acc = 0;
  for (int i = 0; i < WW; i++) { acc += ws->colhist[img][p][i]; if (acc > mid) { cx = i; break; } }
  acc = 0;
  for (int i = 0; i < HH; i++) { acc += ws->rowhist[img][p][i]; if (acc > mid) { cy = i; break; } }
  float sm0 = ws->sigsum0[img][p] / cf;
  float sm1 = ws->sigsum1[img][p] / cf;
  ws->medx[img][p] = basef(cx);
  ws->medy[img][p] = basef(cy);
  ws->sm0a[img][p] = sm0;
  ws->sm1a[img][p] = sm1;
  ws->s0a[img][p] = __expf(10.f * sm0);
  ws->s1a[img][p] = __expf(10.f * sm1);
  ws->validf[img][p] = vf;
  ws->cntf[img][p] = cf;
}

// ---------------- pass 3: medoid argmin (first-index tie-break via 64-bit key)
// grid-stride, 128 blocks/image -> atomicMin depth 128 per address.
__global__ __launch_bounds__(256) void k_argmin(const int* __restrict__ inst,
                                                const int* __restrict__ lab,
                                                WS* __restrict__ ws) {
  int img = blockIdx.y;
  __shared__ unsigned long long skey[PAIRS];
  if (threadIdx.x < PAIRS) skey[threadIdx.x] = ~0ULL;
  __syncthreads();
  float mx[PAIRS], my[PAIRS];
#pragma unroll
  for (int p = 0; p < PAIRS; p++) { mx[p] = ws->medx[img][p]; my[p] = ws->medy[img][p]; }
  for (int pix = blockIdx.x * 256 + threadIdx.x; pix < NPIX; pix += 128 * 256) {
    int l = lab[img * NPIX + pix], it = inst[img * NPIX + pix];
    int pr = pair_of(l, it);
    if (pr >= 0) {
      int x = pix % WW, y = pix / WW;
      float dx = basef(x) - mx[pr];
      float dy = basef(y) - my[pr];
      float d = dx * dx + dy * dy;
      unsigned long long key = ((unsigned long long)__float_as_uint(d) << 32) | (unsigned int)pix;
      atomicMin(&skey[pr], key);
    }
  }
  __syncthreads();
  if (threadIdx.x < PAIRS && skey[threadIdx.x] != ~0ULL)
    atomicMin(&ws->argkey[img][threadIdx.x], skey[threadIdx.x]);
}

// ---------------- pass 4 (heavy): per-(img,pair) dist map -> error histograms; fused var/seed_in
__global__ __launch_bounds__(256) void k_hist(const float* __restrict__ pred,
                                              const int* __restrict__ inst,
                                              const int* __restrict__ lab,
                                              WS* __restrict__ ws) {
  int chunk = blockIdx.x;    // 0..NB5-1
  int p = blockIdx.y;        // 0..PAIRS-1
  int img = blockIdx.z;      // 0..NIMG-1
  __shared__ unsigned int hin_s[BINS];
  __shared__ unsigned int hout_s[2 * BINS];   // 2 lane-parity sub-copies
  for (int k = threadIdx.x; k < BINS; k += 256) hin_s[k] = 0;
  for (int k = threadIdx.x; k < 2 * BINS; k += 256) hout_s[k] = 0;
  __syncthreads();
  if (ws->cnt[img][p] == 0) return;   // uniform across block

  unsigned long long key = ws->argkey[img][p];
  int imin = (int)(key & 0xffffffffu);
  float cx = basef(imin % WW);
  float cy = basef(imin / WW);
  float S0 = ws->s0a[img][p], S1 = ws->s1a[img][p];
  float m0 = ws->sm0a[img][p], m1 = ws->sm1a[img][p];
  int ci = p / MAXID;
  int cl = ci + 1, iid = (p % MAXID) + 1;
  const float* pb = pred + (size_t)img * NCH * NPIX;
  const int* lb = lab + img * NPIX;
  const int* ib = inst + img * NPIX;
  const float* e0b = ws->emb0[img];
  const float* e1b = ws->emb1[img];

  float vpart = 0.f, spart = 0.f;
  int base = chunk * PXB;
  int sub = (threadIdx.x & 1) * BINS;
#pragma unroll 4
  for (int i = 0; i < PXB / 256; i++) {
    int pix = base + i * 256 + threadIdx.x;
    float dx = e0b[pix] - cx;
    float dy = e1b[pix] - cy;
    float q = dx * dx * S0 + dy * dy * S1;
    float d = __expf(-q);
    bool m = (lb[pix] == cl) && (ib[pix] == iid);
    float e = m ? (2.f - 2.f * d) : (2.f * d);
    int bin = (int)(e * (BINS * 0.5f));
    bin = bin > (BINS - 1) ? (BINS - 1) : (bin < 0 ? 0 : bin);
    if (m) {
      atomicAdd(&hin_s[bin], 1u);
      float g0 = pb[2 * NPIX + pix] - m0;
      float g1 = pb[3 * NPIX + pix] - m1;
      vpart += g0 * g0 + g1 * g1;
      float sd = 1.f / (1.f + __expf(-pb[(4 + ci) * NPIX + pix])) - d;
      spart += sd * sd;
    } else {
      atomicAdd(&hout_s[sub + bin], 1u);
    }
  }
  __syncthreads();
  // packed u64 flush: two u32 bins per atomic (counts << 2^32, no carry)
  for (int k = threadIdx.x * 2; k < BINS; k += 512) {
    unsigned long long vi = (unsigned long long)hin_s[k] |
                            ((unsigned long long)hin_s[k + 1] << 32);
    if (vi) atomicAdd((unsigned long long*)&ws->hin[img][p][k], vi);
    unsigned long long vo = (unsigned long long)(hout_s[k] + hout_s[BINS + k]) |
                            ((unsigned long long)(hout_s[k + 1] + hout_s[BINS + k + 1]) << 32);
    if (vo) atomicAdd((unsigned long long*)&ws->hout[img][p][k], vo);
  }
  for (int o = 32; o; o >>= 1) { vpart += __shfl_down(vpart, o); spart += __shfl_down(spart, o); }
  __shared__ float sv, ss;
  if (threadIdx.x == 0) { sv = 0.f; ss = 0.f; }
  __syncthreads();
  if ((threadIdx.x & 63) == 0) { atomicAdd(&sv, vpart); atomicAdd(&ss, spart); }
  __syncthreads();
  if (threadIdx.x == 0) {
    atomicAdd(&ws->varsum[img][p], sv);
    atomicAdd(&ws->seedin[img][p], ss);
  }
}

// ---------------- pass 5: lovasz = (2/BINS) * (0.5 + sum_{k=1}^{B-1} jac(edge_k))
__global__ __launch_bounds__(256) void k_lovasz(WS* __restrict__ ws) {
  int b = blockIdx.x / PAIRS, p = blockIdx.x % PAIRS;
  unsigned int gts = ws->cnt[b][p];
  if (gts == 0) { if (threadIdx.x == 0) ws->lov[b][p] = 0.f; return; }
  __shared__ unsigned int tin[256], tout[256];
  unsigned int lin[8], lout[8];
  unsigned int si = 0, so = 0;
  int k0 = threadIdx.x * 8;
#pragma unroll
  for (int j = 0; j < 8; j++) {
    lin[j] = ws->hin[b][p][k0 + j];
    lout[j] = ws->hout[b][p][k0 + j];
    si += lin[j]; so += lout[j];
  }
  tin[threadIdx.x] = si; tout[threadIdx.x] = so;
  __syncthreads();
  if (threadIdx.x == 0) {   // exclusive suffix scan of per-thread totals
    unsigned int ri = 0, ro = 0;
    for (int t = 255; t >= 0; t--) {
      unsigned int a = tin[t], c = tout[t];
      tin[t] = ri; tout[t] = ro;
      ri += a; ro += c;
    }
  }
  __syncthreads();
  unsigned int Sin = tin[threadIdx.x], Sout = tout[threadIdx.x];
  float gtsf = (float)gts;
  float js = 0.f;
#pragma unroll
  for (int j = 7; j >= 0; j--) {
    Sin += lin[j]; Sout += lout[j];
    int k = k0 + j;
    if (k >= 1) {
      float jac = 1.f - (float)(gts - Sin) / (gtsf + (float)Sout);
      js += jac;
    }
  }
  for (int o = 32; o; o >>= 1) js += __shfl_down(js, o);
  __shared__ float wsum[4];
  if ((threadIdx.x & 63) == 0) wsum[threadIdx.x >> 6] = js;
  __syncthreads();
  if (threadIdx.x == 0) {
    float s = wsum[0] + wsum[1] + wsum[2] + wsum[3];
    ws->lov[b][p] = (2.f / BINS) * (0.5f + s);
  }
}

// ---------------- pass 6: combine
__global__ void k_final(WS* __restrict__ ws, float* __restrict__ out) {
  if (threadIdx.x == 0 && blockIdx.x == 0) {
    float tot = 0.f;
    for (int b = 0; b < NIMG; b++) {
      float lovs = 0.f, vars = 0.f, sins = 0.f, objs = 0.f;
      for (int p = 0; p < PAIRS; p++) {
        float vf = ws->validf[b][p];
        objs += vf;
        lovs += vf * ws->lov[b][p];
        vars += vf * ws->varsum[b][p] / (ws->cntf[b][p] * 2.f);  // /(cnts*NS)
        sins += vf * ws->seedin[b][p];                            // class_weight = 1
      }
      if (objs < 1.f) objs = 1.f;
      float seed_bg = ws->seedT[b] - ws->seedOwn[b];
      float seed_loss = (seed_bg + sins) / (float)NPIX;
      tot += lovs / objs + 10.f * vars / objs + seed_loss;
    }
    out[0] = tot * 0.5f;
  }
}

extern "C" void kernel_launch(void* const* d_in, const int* in_sizes, int n_in,
                              void* d_out, int out_size, void* d_ws, size_t ws_size,
                              hipStream_t stream) {
  const float* pred = (const float*)d_in[0];
  const int* inst = (const int*)d_in[1];
  const int* lab = (const int*)d_in[2];
  WS* ws = (WS*)d_ws;

  size_t zoff = offsetof(WS, cnt);
  size_t zend = offsetof(WS, emb0);
  hipMemsetAsync((char*)d_ws, 0xFF, zoff, stream);                 // argmin keys -> u64 max
  hipMemsetAsync((char*)d_ws + zoff, 0, zend - zoff, stream);      // accumulators -> 0

  k_pass1<<<dim3(HH / 4, NIMG), 256, 0, stream>>>(pred, inst, lab, ws);
  k_medoid<<<1, 64, 0, stream>>>(ws);
  k_argmin<<<dim3(128, NIMG), 256, 0, stream>>>(inst, lab, ws);
  k_hist<<<dim3(NB5, PAIRS, NIMG), 256, 0, stream>>>(pred, inst, lab, ws);
  k_lovasz<<<dim3(NIMG * PAIRS), 256, 0, stream>>>(ws);
  k_final<<<1, 64, 0, stream>>>(ws, (float*)d_out);
}

// Round 3
// 138.182 us; speedup vs baseline: 6.0461x; 2.2018x over previous
//
#include <hip/hip_runtime.h>
#include <cstddef>
#include <cstdint>

// SpatialEmbLoss on MI355X.
// H=W=768, 2 images, NC=5 classes, MAX_ID=3 -> 15 (class,id) pairs per image.
// Lovasz hinge via 2048-bin error histogram:
//   lov = integral_0^2 jac(t) dt,  jac(t) = 1 - (gts - n_in(t))/(gts + n_out(t))
// Round 3: k_hist was latency-bound at 22.8% occupancy (540 blocks) with 24B/iter.
// Now 2160 blocks (PXB=8192, 6 resident/CU at 24KB LDS), 9B/iter via precomputed
// pair-index byte + interleaved float2 emb, 4px/thread float4 loads. Wave-parallel
// k_medoid scan; pridx-based k_argmin.

#define HH 768
#define WW 768
#define NPIX (HH*WW)            // 589824
#define NCL 5
#define MAXID 3
#define PAIRS (NCL*MAXID)       // 15
#define NIMG 2
#define NCH 9                   // 2 emb + 2 sigma + 5 seed channels
#define BINS 2048
#define PXB 8192                // pixels per k_hist block
#define NB5 (NPIX/PXB)          // 72 chunks per (img,pair)

struct WS {
  unsigned long long argkey[NIMG][PAIRS];   // init 0xFF (atomicMin keys)
  // ---------- zero region from here ----------
  unsigned int cnt[NIMG][PAIRS];
  unsigned int colhist[NIMG][PAIRS][WW];
  unsigned int rowhist[NIMG][PAIRS][HH];
  float sigsum0[NIMG][PAIRS];
  float sigsum1[NIMG][PAIRS];
  float seedT[NIMG];            // sum over pixels,classes of sigmoid^2
  float seedOwn[NIMG];          // sum over pixels of own-class sigmoid^2
  alignas(8) unsigned int hin[NIMG][PAIRS][BINS];
  alignas(8) unsigned int hout[NIMG][PAIRS][BINS];
  float varsum[NIMG][PAIRS];
  float seedin[NIMG][PAIRS];
  float medx[NIMG][PAIRS], medy[NIMG][PAIRS];
  float s0a[NIMG][PAIRS], s1a[NIMG][PAIRS];
  float sm0a[NIMG][PAIRS], sm1a[NIMG][PAIRS];
  float validf[NIMG][PAIRS], cntf[NIMG][PAIRS];
  float lov[NIMG][PAIRS];
  // ---------- end zero region ----------
  alignas(16) float2 emb[NIMG][NPIX];      // {tanh(p0)+x, tanh(p1)+y}
  unsigned char pridx[NIMG][NPIX];         // pair index 0..14, 255 = none
};

__device__ __forceinline__ float basef(int i) {
  // jnp.linspace(0,1,1024)[i]
  return (float)i * (1.0f / 1023.0f);
}

__device__ __forceinline__ int pair_of(int l, int it) {
  return (l >= 1 && l <= NCL && it >= 1 && it <= MAXID) ? (l - 1) * MAXID + (it - 1) : -1;
}

// ---------------- pass 1: counts, row/col hists, sigma sums, seed sums, emb+pridx precompute
__global__ __launch_bounds__(256) void k_pass1(const float* __restrict__ pred,
                                               const int* __restrict__ inst,
                                               const int* __restrict__ lab,
                                               WS* __restrict__ ws) {
  int img = blockIdx.y;
  int y0 = blockIdx.x * 4;
  const float* p = pred + (size_t)img * NCH * NPIX;
  const int* lb = lab + img * NPIX;
  const int* ib = inst + img * NPIX;

  __shared__ unsigned int scnt[PAIRS];
  __shared__ float ssig0[PAIRS], ssig1[PAIRS];
  __shared__ unsigned int srow[4 * PAIRS];
  __shared__ float sT, sO;
  if (threadIdx.x < PAIRS) { scnt[threadIdx.x] = 0; ssig0[threadIdx.x] = 0.f; ssig1[threadIdx.x] = 0.f; }
  if (threadIdx.x < 4 * PAIRS) srow[threadIdx.x] = 0;
  if (threadIdx.x == 0) { sT = 0.f; sO = 0.f; }
  __syncthreads();

  float t = 0.f, own = 0.f;
#pragma unroll
  for (int i = 0; i < 12; i++) {
    int off = i * 256 + threadIdx.x;       // 0..3071
    int rl = off / WW;                      // 0..3
    int x = off - rl * WW;
    int y = y0 + rl;
    int pix = y0 * WW + off;
    int l = lb[pix];
    int it = ib[pix];

    // seed maps: sigmoid(pred[4+c])^2
#pragma unroll
    for (int c = 0; c < NCL; ++c) {
      float z = p[(4 + c) * NPIX + pix];
      float s = 1.f / (1.f + __expf(-z));
      float s2 = s * s;
      t += s2;
      if (l == c + 1) own = own + s2;
    }

    // embedding + pair index precompute
    float e0 = tanhf(p[0 * NPIX + pix]) + basef(x);
    float e1 = tanhf(p[1 * NPIX + pix]) + basef(y);
    ws->emb[img][pix] = make_float2(e0, e1);
    int pr = pair_of(l, it);
    ws->pridx[img][pix] = (unsigned char)(pr >= 0 ? pr : 255);

    if (pr >= 0) {
      atomicAdd(&scnt[pr], 1u);
      atomicAdd(&ssig0[pr], p[2 * NPIX + pix]);
      atomicAdd(&ssig1[pr], p[3 * NPIX + pix]);
      atomicAdd(&srow[rl * PAIRS + pr], 1u);
      atomicAdd(&ws->colhist[img][pr][x], 1u);   // spread over 11520 addrs
    }
  }

  // seed scalars: wave reduce -> LDS -> one global atomic per block
  for (int o = 32; o; o >>= 1) { t += __shfl_down(t, o); own += __shfl_down(own, o); }
  if ((threadIdx.x & 63) == 0) { atomicAdd(&sT, t); atomicAdd(&sO, own); }
  __syncthreads();
  if (threadIdx.x == 0) {
    atomicAdd(&ws->seedT[img], sT);
    atomicAdd(&ws->seedOwn[img], sO);
  }
  if (threadIdx.x < PAIRS) {
    unsigned int c = scnt[threadIdx.x];
    if (c) {
      atomicAdd(&ws->cnt[img][threadIdx.x], c);
      atomicAdd(&ws->sigsum0[img][threadIdx.x], ssig0[threadIdx.x]);
      atomicAdd(&ws->sigsum1[img][threadIdx.x], ssig1[threadIdx.x]);
    }
  }
  if (threadIdx.x < 4 * PAIRS) {
    unsigned int v = srow[threadIdx.x];
    if (v) {
      int rl = threadIdx.x / PAIRS, pr = threadIdx.x % PAIRS;
      atomicAdd(&ws->rowhist[img][pr][y0 + rl], v);
    }
  }
}

// ---------------- pass 2: medians from histograms (block-parallel scan), sigma means
// one block per (img,pair); 768 = 256*3 bins scanned via Hillis-Steele in LDS.
__global__ __launch_bounds__(256) void k_medoid(WS* __restrict__ ws) {
  int img = blockIdx.x / PAIRS, p = blockIdx.x % PAIRS;
  unsigned int c = ws->cnt[img][p];
  unsigned int target = (c > 0) ? (((c - 1u) >> 1) + 1u) : 1u;  // (mid+1)-th order stat
  __shared__ unsigned int pref[256];
  __shared__ int cross;
  int res[2];
#pragma unroll
  for (int h = 0; h < 2; h++) {
    const unsigned int* hist = h ? ws->rowhist[img][p] : ws->colhist[img][p];
    unsigned int v0 = hist[threadIdx.x * 3 + 0];
    unsigned int v1 = hist[threadIdx.x * 3 + 1];
    unsigned int v2 = hist[threadIdx.x * 3 + 2];
    unsigned int s = v0 + v1 + v2;
    pref[threadIdx.x] = s;
    __syncthreads();
    for (int d = 1; d < 256; d <<= 1) {
      unsigned int tv = (threadIdx.x >= d) ? pref[threadIdx.x - d] : 0u;
      __syncthreads();
      pref[threadIdx.x] += tv;
      __syncthreads();
    }
    if (threadIdx.x == 0) cross = 0;
    __syncthreads();
    unsigned int inc = pref[threadIdx.x];
    unsigned int exc = inc - s;
    if (inc >= target && exc < target) {
      int j = (exc + v0 >= target) ? 0 : ((exc + v0 + v1 >= target) ? 1 : 2);
      cross = threadIdx.x * 3 + j;
    }
    __syncthreads();
    res[h] = cross;
    __syncthreads();
  }
  if (threadIdx.x == 0) {
    float vf = (c > 0) ? 1.f : 0.f;
    float cf = (c > 0) ? (float)c : 1.f;
    float sm0 = ws->sigsum0[img][p] / cf;
    float sm1 = ws->sigsum1[img][p] / cf;
    ws->medx[img][p] = basef(res[0]);
    ws->medy[img][p] = basef(res[1]);
    ws->sm0a[img][p] = sm0;
    ws->sm1a[img][p] = sm1;
    ws->s0a[img][p] = __expf(10.f * sm0);
    ws->s1a[img][p] = __expf(10.f * sm1);
    ws->validf[img][p] = vf;
    ws->cntf[img][p] = cf;
  }
}

// ---------------- pass 3: medoid argmin (first-index tie-break via 64-bit key)
// 144 blocks/img, 4 px/thread via uchar4, pridx-based.
__global__ __launch_bounds__(256) void k_argmin(WS* __restrict__ ws) {
  int img = blockIdx.y;
  __shared__ unsigned long long skey[PAIRS];
  if (threadIdx.x < PAIRS) skey[threadIdx.x] = ~0ULL;
  __syncthreads();
  const unsigned char* prb = ws->pridx[img];
  int base = blockIdx.x * 4096;
#pragma unroll
  for (int j = 0; j < 4; j++) {
    int px0 = base + j * 1024 + threadIdx.x * 4;
    uchar4 pr4 = *(const uchar4*)(prb + px0);
#pragma unroll
    for (int k = 0; k < 4; k++) {
      int pr = (k == 0) ? pr4.x : (k == 1) ? pr4.y : (k == 2) ? pr4.z : pr4.w;
      if (pr != 255) {
        int pix = px0 + k;
        int y = pix / WW, x = pix - y * WW;
        float dx = basef(x) - ws->medx[img][pr];
        float dy = basef(y) - ws->medy[img][pr];
        float d = dx * dx + dy * dy;
        unsigned long long key = ((unsigned long long)__float_as_uint(d) << 32) | (unsigned int)pix;
        atomicMin(&skey[pr], key);
      }
    }
  }
  __syncthreads();
  if (threadIdx.x < PAIRS && skey[threadIdx.x] != ~0ULL)
    atomicMin(&ws->argkey[img][threadIdx.x], skey[threadIdx.x]);
}

// ---------------- pass 4 (heavy): per-(img,pair) dist map -> error histograms; fused var/seed_in
__device__ __forceinline__ void do_px(int pix, float ex, float ey, int prx,
    int p, float cx, float cy, float S0, float S1, float m0, float m1,
    const float* __restrict__ pb, int ci,
    unsigned int* hin_s, unsigned int* hout_s, int sub,
    float& vpart, float& spart) {
  float dx = ex - cx, dy = ey - cy;
  float q = dx * dx * S0 + dy * dy * S1;
  float d = __expf(-q);
  bool m = (prx == p);
  float e = m ? (2.f - 2.f * d) : (2.f * d);
  int bin = (int)(e * (BINS * 0.5f));
  bin = bin > (BINS - 1) ? (BINS - 1) : (bin < 0 ? 0 : bin);
  if (m) {
    atomicAdd(&hin_s[bin], 1u);
    float g0 = pb[2 * NPIX + pix] - m0;
    float g1 = pb[3 * NPIX + pix] - m1;
    vpart += g0 * g0 + g1 * g1;
    float sd = 1.f / (1.f + __expf(-pb[(4 + ci) * NPIX + pix])) - d;
    spart += sd * sd;
  } else {
    atomicAdd(&hout_s[sub + bin], 1u);
  }
}

__global__ __launch_bounds__(256) void k_hist(const float* __restrict__ pred,
                                              WS* __restrict__ ws) {
  int chunk = blockIdx.x;    // 0..NB5-1
  int p = blockIdx.y;        // 0..PAIRS-1
  int img = blockIdx.z;      // 0..NIMG-1
  if (ws->cnt[img][p] == 0) return;   // uniform across block

  __shared__ unsigned int hin_s[BINS];
  __shared__ unsigned int hout_s[2 * BINS];   // 2 lane-parity sub-copies
  for (int k = threadIdx.x; k < BINS; k += 256) hin_s[k] = 0;
  for (int k = threadIdx.x; k < 2 * BINS; k += 256) hout_s[k] = 0;
  __syncthreads();

  unsigned long long key = ws->argkey[img][p];
  int imin = (int)(key & 0xffffffffu);
  float cx = basef(imin % WW);
  float cy = basef(imin / WW);
  float S0 = ws->s0a[img][p], S1 = ws->s1a[img][p];
  float m0 = ws->sm0a[img][p], m1 = ws->sm1a[img][p];
  int ci = p / MAXID;
  const float* pb = pred + (size_t)img * NCH * NPIX;
  const float* embb = (const float*)ws->emb[img];
  const unsigned char* prb = ws->pridx[img];

  float vpart = 0.f, spart = 0.f;
  int base = chunk * PXB;
  int sub = (threadIdx.x & 1) * BINS;
#pragma unroll 2
  for (int j = 0; j < PXB / 1024; j++) {     // 8 iters, 4 px each
    int px0 = base + j * 1024 + threadIdx.x * 4;
    float4 eA = *(const float4*)(embb + 2 * px0);       // px0, px1
    float4 eB = *(const float4*)(embb + 2 * px0 + 4);   // px2, px3
    uchar4 pr4 = *(const uchar4*)(prb + px0);
    do_px(px0 + 0, eA.x, eA.y, pr4.x, p, cx, cy, S0, S1, m0, m1, pb, ci, hin_s, hout_s, sub, vpart, spart);
    do_px(px0 + 1, eA.z, eA.w, pr4.y, p, cx, cy, S0, S1, m0, m1, pb, ci, hin_s, hout_s, sub, vpart, spart);
    do_px(px0 + 2, eB.x, eB.y, pr4.z, p, cx, cy, S0, S1, m0, m1, pb, ci, hin_s, hout_s, sub, vpart, spart);
    do_px(px0 + 3, eB.z, eB.w, pr4.w, p, cx, cy, S0, S1, m0, m1, pb, ci, hin_s, hout_s, sub, vpart, spart);
  }
  __syncthreads();
  // packed u64 flush: two u32 bins per atomic (counts << 2^32, no carry); skip zeros
  for (int k = threadIdx.x * 2; k < BINS; k += 512) {
    unsigned long long vi = (unsigned long long)hin_s[k] |
                            ((unsigned long long)hin_s[k + 1] << 32);
    if (vi) atomicAdd((unsigned long long*)&ws->hin[img][p][k], vi);
    unsigned long long vo = (unsigned long long)(hout_s[k] + hout_s[BINS + k]) |
                            ((unsigned long long)(hout_s[k + 1] + hout_s[BINS + k + 1]) << 32);
    if (vo) atomicAdd((unsigned long long*)&ws->hout[img][p][k], vo);
  }
  for (int o = 32; o; o >>= 1) { vpart += __shfl_down(vpart, o); spart += __shfl_down(spart, o); }
  __shared__ float sv, ss;
  if (threadIdx.x == 0) { sv = 0.f; ss = 0.f; }
  __syncthreads();
  if ((threadIdx.x & 63) == 0) { atomicAdd(&sv, vpart); atomicAdd(&ss, spart); }
  __syncthreads();
  if (threadIdx.x == 0) {
    atomicAdd(&ws->varsum[img][p], sv);
    atomicAdd(&ws->seedin[img][p], ss);
  }
}

// ---------------- pass 5: lovasz = (2/BINS) * (0.5 + sum_{k=1}^{B-1} jac(edge_k))
__global__ __launch_bounds__(256) void k_lovasz(WS* __restrict__ ws) {
  int b = blockIdx.x / PAIRS, p = blockIdx.x % PAIRS;
  unsigned int gts = ws->cnt[b][p];
  if (gts == 0) { if (threadIdx.x == 0) ws->lov[b][p] = 0.f; return; }
  __shared__ unsigned int tin[256], tout[256];
  unsigned int lin[8], lout[8];
  unsigned int si = 0, so = 0;
  int k0 = threadIdx.x * 8;
#pragma unroll
  for (int j = 0; j < 8; j++) {
    lin[j] = ws->hin[b][p][k0 + j];
    lout[j] = ws->hout[b][p][k0 + j];
    si += lin[j]; so += lout[j];
  }
  tin[threadIdx.x] = si; tout[threadIdx.x] = so;
  __syncthreads();
  if (threadIdx.x == 0) {   // exclusive suffix scan of per-thread totals
    unsigned int ri = 0, ro = 0;
    for (int t = 255; t >= 0; t--) {
      unsigned int a = tin[t], c = tout[t];
      tin[t] = ri; tout[t] = ro;
      ri += a; ro += c;
    }
  }
  __syncthreads();
  unsigned int Sin = tin[threadIdx.x], Sout = tout[threadIdx.x];
  float gtsf = (float)gts;
  float js = 0.f;
#pragma unroll
  for (int j = 7; j >= 0; j--) {
    Sin += lin[j]; Sout += lout[j];
    int k = k0 + j;
    if (k >= 1) {
      float jac = 1.f - (float)(gts - Sin) / (gtsf + (float)Sout);
      js += jac;
    }
  }
  for (int o = 32; o; o >>= 1) js += __shfl_down(js, o);
  __shared__ float wsum[4];
  if ((threadIdx.x & 63) == 0) wsum[threadIdx.x >> 6] = js;
  __syncthreads();
  if (threadIdx.x == 0) {
    float s = wsum[0] + wsum[1] + wsum[2] + wsum[3];
    ws->lov[b][p] = (2.f / BINS) * (0.5f + s);
  }
}

// ---------------- pass 6: combine
__global__ void k_final(WS* __restrict__ ws, float* __restrict__ out) {
  if (threadIdx.x == 0 && blockIdx.x == 0) {
    float tot = 0.f;
    for (int b = 0; b < NIMG; b++) {
      float lovs = 0.f, vars = 0.f, sins = 0.f, objs = 0.f;
      for (int p = 0; p < PAIRS; p++) {
        float vf = ws->validf[b][p];
        objs += vf;
        lovs += vf * ws->lov[b][p];
        vars += vf * ws->varsum[b][p] / (ws->cntf[b][p] * 2.f);  // /(cnts*NS)
        sins += vf * ws->seedin[b][p];                            // class_weight = 1
      }
      if (objs < 1.f) objs = 1.f;
      float seed_bg = ws->seedT[b] - ws->seedOwn[b];
      float seed_loss = (seed_bg + sins) / (float)NPIX;
      tot += lovs / objs + 10.f * vars / objs + seed_loss;
    }
    out[0] = tot * 0.5f;
  }
}

extern "C" void kernel_launch(void* const* d_in, const int* in_sizes, int n_in,
                              void* d_out, int out_size, void* d_ws, size_t ws_size,
                              hipStream_t stream) {
  const float* pred = (const float*)d_in[0];
  const int* inst = (const int*)d_in[1];
  const int* lab = (const int*)d_in[2];
  WS* ws = (WS*)d_ws;

  size_t zoff = offsetof(WS, cnt);
  size_t zend = offsetof(WS, emb);
  hipMemsetAsync((char*)d_ws, 0xFF, zoff, stream);                 // argmin keys -> u64 max
  hipMemsetAsync((char*)d_ws + zoff, 0, zend - zoff, stream);      // accumulators -> 0

  k_pass1<<<dim3(HH / 4, NIMG), 256, 0, stream>>>(pred, inst, lab, ws);
  k_medoid<<<dim3(NIMG * PAIRS), 256, 0, stream>>>(ws);
  k_argmin<<<dim3(NPIX / 4096, NIMG), 256, 0, stream>>>(ws);
  k_hist<<<dim3(NB5, PAIRS, NIMG), 256, 0, stream>>>(pred, ws);
  k_lovasz<<<dim3(NIMG * PAIRS), 256, 0, stream>>>(ws);
  k_final<<<1, 64, 0, stream>>>(ws, (float*)d_out);
}